// Round 1
// baseline (9361.221 us; speedup 1.0000x reference)
//
#include <hip/hip_runtime.h>
#include <hip/hip_bf16.h>
#include <math.h>

#define S_TOT 1536
#define S0    1024
#define HID   1024
#define HEADS 16
#define HD    64
#define INTER 4096
#define NLAYERS 4
#define KCONV 768
#define EPSV  1e-5f
#define SCALEV 0.125f

// ---------------- im2col ----------------
// P[s][k], k = c*256 + y*16 + x
__global__ __launch_bounds__(256) void im2col_kernel(
    const float* __restrict__ img0, const float* __restrict__ img1,
    float* __restrict__ P)
{
    int s = blockIdx.x;
    const float* img; int W, ph, pw;
    if (s < S0) { img = img0; W = 512; ph = s >> 5; pw = s & 31; }
    else { int t = s - S0; img = img1; W = 256; ph = t >> 4; pw = t & 15; }
    for (int k = threadIdx.x; k < KCONV; k += 256) {
        int c = k >> 8; int r = k & 255; int y = r >> 4; int x = r & 15;
        P[(size_t)s * KCONV + k] = img[(size_t)c * 512 * W + (size_t)(ph * 16 + y) * W + (pw * 16 + x)];
    }
}

// ---------------- fp32 SGEMM: C[M][N] = A[M][K] * B[N][K]^T (+ D) ----------------
#define BM 64
#define BN 64
#define BK 16
__global__ __launch_bounds__(256) void sgemm_btn(
    const float* __restrict__ A, const float* __restrict__ B,
    const float* __restrict__ D, float* __restrict__ C,
    int M, int N, int K)
{
    __shared__ float As[BK][BM + 4];
    __shared__ float Bs[BK][BN + 4];
    int t = threadIdx.x;
    int bm = blockIdx.x * BM;
    int bn = blockIdx.y * BN;
    int tm = (t & 15) * 4;
    int tn = (t >> 4) * 4;
    int lr = t >> 2;          // 0..63 tile row
    int lk = (t & 3) * 4;     // 0,4,8,12
    float acc[4][4] = {};
    for (int k0 = 0; k0 < K; k0 += BK) {
        float4 av = *(const float4*)(A + (size_t)(bm + lr) * K + k0 + lk);
        float4 bv = *(const float4*)(B + (size_t)(bn + lr) * K + k0 + lk);
        As[lk + 0][lr] = av.x; As[lk + 1][lr] = av.y; As[lk + 2][lr] = av.z; As[lk + 3][lr] = av.w;
        Bs[lk + 0][lr] = bv.x; Bs[lk + 1][lr] = bv.y; Bs[lk + 2][lr] = bv.z; Bs[lk + 3][lr] = bv.w;
        __syncthreads();
        #pragma unroll
        for (int kk = 0; kk < BK; ++kk) {
            float4 a4 = *(const float4*)&As[kk][tm];
            float4 b4 = *(const float4*)&Bs[kk][tn];
            float ar[4] = {a4.x, a4.y, a4.z, a4.w};
            float br[4] = {b4.x, b4.y, b4.z, b4.w};
            #pragma unroll
            for (int i = 0; i < 4; ++i)
                #pragma unroll
                for (int j = 0; j < 4; ++j)
                    acc[i][j] = fmaf(ar[i], br[j], acc[i][j]);
        }
        __syncthreads();
    }
    #pragma unroll
    for (int i = 0; i < 4; ++i) {
        int row = bm + tm + i;
        #pragma unroll
        for (int j = 0; j < 4; ++j) {
            int col = bn + tn + j;
            float v = acc[i][j];
            if (D) v += D[(size_t)row * N + col];
            C[(size_t)row * N + col] = v;
        }
    }
}

// ---------------- RMS norm (block per row) ----------------
__global__ __launch_bounds__(256) void rms_kernel(
    const float* __restrict__ in, const float* __restrict__ w,
    float* __restrict__ out, int ncols)
{
    int row = blockIdx.x;
    const float* xr = in + (size_t)row * ncols;
    float ss = 0.f;
    for (int i = threadIdx.x; i < ncols; i += 256) { float v = xr[i]; ss += v * v; }
    #pragma unroll
    for (int off = 32; off > 0; off >>= 1) ss += __shfl_down(ss, off, 64);
    __shared__ float red[4];
    int wid = threadIdx.x >> 6;
    if ((threadIdx.x & 63) == 0) red[wid] = ss;
    __syncthreads();
    if (threadIdx.x == 0) {
        float s = red[0] + red[1] + red[2] + red[3];
        red[0] = rsqrtf(s / ncols + EPSV);
    }
    __syncthreads();
    float rs = red[0];
    for (int i = threadIdx.x; i < ncols; i += 256)
        out[(size_t)row * ncols + i] = xr[i] * rs * w[i];
}

// ---------------- RoPE tables: cs/sn [S][32] ----------------
__global__ void rope_tab_kernel(float* __restrict__ cs, float* __restrict__ sn)
{
    int s = blockIdx.x; int j = threadIdx.x; // 32 threads
    int h, w;
    if (s < S0) { h = s >> 5; w = s & 31; }
    else { int t = s - S0; h = t >> 4; w = t & 15; }
    float f;
    if (j < 16) f = (float)h * powf(10000.f, -(4.f * j) / 64.f);
    else        f = (float)w * powf(10000.f, -(4.f * (j - 16) + 2.f) / 64.f);
    cs[s * 32 + j] = cosf(f);
    sn[s * 32 + j] = sinf(f);
}

// ---------------- RoPE apply (in-place on q and k) ----------------
__global__ __launch_bounds__(256) void rope_apply_kernel(
    float* __restrict__ q, float* __restrict__ k,
    const float* __restrict__ cs, const float* __restrict__ sn)
{
    int idx = blockIdx.x * 256 + threadIdx.x;  // S*HEADS*32
    int s = idx / (HEADS * 32);
    int r = idx % (HEADS * 32);
    int hh = r >> 5; int j = r & 31;
    float c = cs[s * 32 + j], sv = sn[s * 32 + j];
    size_t base = (size_t)s * HID + hh * HD + j;
    float a = q[base], b = q[base + 32];
    q[base] = a * c - b * sv; q[base + 32] = b * c + a * sv;
    a = k[base]; b = k[base + 32];
    k[base] = a * c - b * sv; k[base + 32] = b * c + a * sv;
}

// ---------------- segmented attention, block per (row, head) ----------------
__global__ __launch_bounds__(256) void attn_kernel(
    const float* __restrict__ q, const float* __restrict__ k,
    const float* __restrict__ v, float* __restrict__ o)
{
    int s = blockIdx.x;
    int hh = blockIdx.y;
    int segStart = (s < S0) ? 0 : S0;
    int segLen   = (s < S0) ? S0 : (S_TOT - S0);
    __shared__ float sc[1024];
    __shared__ float qv[64];
    __shared__ float red[256];
    int t = threadIdx.x;
    if (t < 64) qv[t] = q[(size_t)s * HID + hh * HD + t];
    __syncthreads();
    float mx = -1e30f;
    for (int kk = t; kk < segLen; kk += 256) {
        const float* kr = k + (size_t)(segStart + kk) * HID + hh * HD;
        float dot = 0.f;
        #pragma unroll
        for (int d = 0; d < 64; d += 4) {
            float4 kv4 = *(const float4*)(kr + d);
            dot = fmaf(qv[d], kv4.x, dot);
            dot = fmaf(qv[d + 1], kv4.y, dot);
            dot = fmaf(qv[d + 2], kv4.z, dot);
            dot = fmaf(qv[d + 3], kv4.w, dot);
        }
        dot *= SCALEV;
        sc[kk] = dot;
        mx = fmaxf(mx, dot);
    }
    red[t] = mx; __syncthreads();
    for (int off = 128; off > 0; off >>= 1) {
        if (t < off) red[t] = fmaxf(red[t], red[t + off]);
        __syncthreads();
    }
    mx = red[0]; __syncthreads();
    float sum = 0.f;
    for (int kk = t; kk < segLen; kk += 256) {
        float e = expf(sc[kk] - mx); sc[kk] = e; sum += e;
    }
    red[t] = sum; __syncthreads();
    for (int off = 128; off > 0; off >>= 1) {
        if (t < off) red[t] += red[t + off];
        __syncthreads();
    }
    float inv = 1.f / red[0];
    __syncthreads();
    int d = t & 63; int c = t >> 6;
    float acc = 0.f;
    for (int kk = c; kk < segLen; kk += 4)
        acc = fmaf(sc[kk], v[(size_t)(segStart + kk) * HID + hh * HD + d], acc);
    red[t] = acc; __syncthreads();
    if (t < 64) {
        float r = red[t] + red[t + 64] + red[t + 128] + red[t + 192];
        o[(size_t)s * HID + hh * HD + d] = r * inv;
    }
}

// ---------------- SiLU(g) * u -> g ----------------
__global__ __launch_bounds__(256) void silu_mul_kernel(
    float* __restrict__ g, const float* __restrict__ u, int n)
{
    int i = blockIdx.x * 256 + threadIdx.x;
    if (i < n) {
        float x = g[i];
        float sg = 1.f / (1.f + expf(-x));
        g[i] = x * sg * u[i];
    }
}

// ---------------- copy to out ----------------
__global__ __launch_bounds__(256) void copy_kernel(
    const float* __restrict__ src, float* __restrict__ dst, int n)
{
    int i = blockIdx.x * 256 + threadIdx.x;
    if (i < n) dst[i] = src[i];
}

extern "C" void kernel_launch(void* const* d_in, const int* in_sizes, int n_in,
                              void* d_out, int out_size, void* d_ws, size_t ws_size,
                              hipStream_t stream)
{
    const float* img0        = (const float*)d_in[0];
    const float* img1        = (const float*)d_in[1];
    const float* conv_w      = (const float*)d_in[2];
    const float* ln_pre_w    = (const float*)d_in[3];
    const float* attn_norm_w = (const float*)d_in[4];
    const float* q_w         = (const float*)d_in[5];
    const float* k_w         = (const float*)d_in[6];
    const float* v_w         = (const float*)d_in[7];
    const float* o_w         = (const float*)d_in[8];
    const float* ffn_norm_w  = (const float*)d_in[9];
    const float* gate_w      = (const float*)d_in[10];
    const float* up_w        = (const float*)d_in[11];
    const float* down_w      = (const float*)d_in[12];

    float* ws = (float*)d_ws;
    const size_t SH = (size_t)S_TOT * HID;     // 1.57M
    const size_t SI = (size_t)S_TOT * INTER;   // 6.29M
    float* x  = ws;
    float* hn = x + SH;
    float* qb = hn + SH;
    float* kb = qb + SH;
    float* vb = kb + SH;
    float* ob = vb + SH;
    float* g  = ob + SH;
    float* u  = g + SI;
    float* cs = u + SI;
    float* sn = cs + (size_t)S_TOT * 32;
    float* P  = qb;  // im2col scratch reuses q buffer (used before q)

    dim3 blk(256);

    // patch embed
    im2col_kernel<<<S_TOT, blk, 0, stream>>>(img0, img1, P);
    {
        dim3 grid(S_TOT / BM, HID / BN);
        sgemm_btn<<<grid, blk, 0, stream>>>(P, conv_w, nullptr, x, S_TOT, HID, KCONV);
    }
    // ln_pre (in-place)
    rms_kernel<<<S_TOT, blk, 0, stream>>>(x, ln_pre_w, x, HID);
    // rope tables
    rope_tab_kernel<<<S_TOT, 32, 0, stream>>>(cs, sn);

    for (int l = 0; l < NLAYERS; ++l) {
        const float* qw = q_w + (size_t)l * HID * HID;
        const float* kw = k_w + (size_t)l * HID * HID;
        const float* vw = v_w + (size_t)l * HID * HID;
        const float* ow = o_w + (size_t)l * HID * HID;
        const float* gw = gate_w + (size_t)l * INTER * HID;
        const float* uw = up_w + (size_t)l * INTER * HID;
        const float* dw = down_w + (size_t)l * HID * INTER;

        rms_kernel<<<S_TOT, blk, 0, stream>>>(x, attn_norm_w + (size_t)l * HID, hn, HID);
        {
            dim3 grid(S_TOT / BM, HID / BN);
            sgemm_btn<<<grid, blk, 0, stream>>>(hn, qw, nullptr, qb, S_TOT, HID, HID);
            sgemm_btn<<<grid, blk, 0, stream>>>(hn, kw, nullptr, kb, S_TOT, HID, HID);
            sgemm_btn<<<grid, blk, 0, stream>>>(hn, vw, nullptr, vb, S_TOT, HID, HID);
        }
        rope_apply_kernel<<<(S_TOT * HEADS * 32) / 256, blk, 0, stream>>>(qb, kb, cs, sn);
        {
            dim3 agrid(S_TOT, HEADS);
            attn_kernel<<<agrid, blk, 0, stream>>>(qb, kb, vb, ob);
        }
        {
            dim3 grid(S_TOT / BM, HID / BN);
            sgemm_btn<<<grid, blk, 0, stream>>>(ob, ow, x, x, S_TOT, HID, HID);  // residual
        }
        rms_kernel<<<S_TOT, blk, 0, stream>>>(x, ffn_norm_w + (size_t)l * HID, hn, HID);
        {
            dim3 grid(S_TOT / BM, INTER / BN);
            sgemm_btn<<<grid, blk, 0, stream>>>(hn, gw, nullptr, g, S_TOT, INTER, HID);
            sgemm_btn<<<grid, blk, 0, stream>>>(hn, uw, nullptr, u, S_TOT, INTER, HID);
        }
        silu_mul_kernel<<<(int)(SI / 256), blk, 0, stream>>>(g, u, (int)SI);
        {
            dim3 grid(S_TOT / BM, HID / BN);
            sgemm_btn<<<grid, blk, 0, stream>>>(g, dw, x, x, S_TOT, HID, INTER);  // residual
        }
    }
    copy_kernel<<<(int)(SH / 256), blk, 0, stream>>>(x, (float*)d_out, (int)SH);
}

// Round 2
// 4750.325 us; speedup vs baseline: 1.9706x; 1.9706x over previous
//
#include <hip/hip_runtime.h>
#include <hip/hip_bf16.h>
#include <math.h>

#define S_TOT 1536
#define S0    1024
#define HID   1024
#define HEADS 16
#define HD    64
#define INTER 4096
#define NLAYERS 4
#define KCONV 768
#define EPSV  1e-5f
#define SCALEV 0.125f

// ---------------- im2col ----------------
// P[s][k], k = c*256 + y*16 + x
__global__ __launch_bounds__(256) void im2col_kernel(
    const float* __restrict__ img0, const float* __restrict__ img1,
    float* __restrict__ P)
{
    int s = blockIdx.x;
    const float* img; int W, ph, pw;
    if (s < S0) { img = img0; W = 512; ph = s >> 5; pw = s & 31; }
    else { int t = s - S0; img = img1; W = 256; ph = t >> 4; pw = t & 15; }
    for (int k = threadIdx.x; k < KCONV; k += 256) {
        int c = k >> 8; int r = k & 255; int y = r >> 4; int x = r & 15;
        P[(size_t)s * KCONV + k] = img[(size_t)c * 512 * W + (size_t)(ph * 16 + y) * W + (pw * 16 + x)];
    }
}

// ---------------- fp32 SGEMM: C[M][N] = A[M][K] * B[N][K]^T (+ D) ----------------
#define BM 64
#define BN 64
#define BK 16
__global__ __launch_bounds__(256) void sgemm_btn(
    const float* __restrict__ A, const float* __restrict__ B,
    const float* __restrict__ D, float* __restrict__ C,
    int M, int N, int K)
{
    __shared__ float As[BK][BM + 4];
    __shared__ float Bs[BK][BN + 4];
    int t = threadIdx.x;
    int bm = blockIdx.x * BM;
    int bn = blockIdx.y * BN;
    int tm = (t & 15) * 4;
    int tn = (t >> 4) * 4;
    int lr = t >> 2;          // 0..63 tile row
    int lk = (t & 3) * 4;     // 0,4,8,12
    float acc[4][4] = {};
    for (int k0 = 0; k0 < K; k0 += BK) {
        float4 av = *(const float4*)(A + (size_t)(bm + lr) * K + k0 + lk);
        float4 bv = *(const float4*)(B + (size_t)(bn + lr) * K + k0 + lk);
        As[lk + 0][lr] = av.x; As[lk + 1][lr] = av.y; As[lk + 2][lr] = av.z; As[lk + 3][lr] = av.w;
        Bs[lk + 0][lr] = bv.x; Bs[lk + 1][lr] = bv.y; Bs[lk + 2][lr] = bv.z; Bs[lk + 3][lr] = bv.w;
        __syncthreads();
        #pragma unroll
        for (int kk = 0; kk < BK; ++kk) {
            float4 a4 = *(const float4*)&As[kk][tm];
            float4 b4 = *(const float4*)&Bs[kk][tn];
            float ar[4] = {a4.x, a4.y, a4.z, a4.w};
            float br[4] = {b4.x, b4.y, b4.z, b4.w};
            #pragma unroll
            for (int i = 0; i < 4; ++i)
                #pragma unroll
                for (int j = 0; j < 4; ++j)
                    acc[i][j] = fmaf(ar[i], br[j], acc[i][j]);
        }
        __syncthreads();
    }
    #pragma unroll
    for (int i = 0; i < 4; ++i) {
        int row = bm + tm + i;
        #pragma unroll
        for (int j = 0; j < 4; ++j) {
            int col = bn + tn + j;
            float v = acc[i][j];
            if (D) v += D[(size_t)row * N + col];
            C[(size_t)row * N + col] = v;
        }
    }
}

// ---------------- RMS norm (block per row) ----------------
__global__ __launch_bounds__(256) void rms_kernel(
    const float* __restrict__ in, const float* __restrict__ w,
    float* __restrict__ out, int ncols)
{
    int row = blockIdx.x;
    const float* xr = in + (size_t)row * ncols;
    float ss = 0.f;
    for (int i = threadIdx.x; i < ncols; i += 256) { float v = xr[i]; ss += v * v; }
    #pragma unroll
    for (int off = 32; off > 0; off >>= 1) ss += __shfl_down(ss, off, 64);
    __shared__ float red[4];
    int wid = threadIdx.x >> 6;
    if ((threadIdx.x & 63) == 0) red[wid] = ss;
    __syncthreads();
    if (threadIdx.x == 0) {
        float s = red[0] + red[1] + red[2] + red[3];
        red[0] = rsqrtf(s / ncols + EPSV);
    }
    __syncthreads();
    float rs = red[0];
    for (int i = threadIdx.x; i < ncols; i += 256)
        out[(size_t)row * ncols + i] = xr[i] * rs * w[i];
}

// ---------------- RoPE tables: cs/sn [S][32] ----------------
__global__ void rope_tab_kernel(float* __restrict__ cs, float* __restrict__ sn)
{
    int s = blockIdx.x; int j = threadIdx.x; // 32 threads
    int h, w;
    if (s < S0) { h = s >> 5; w = s & 31; }
    else { int t = s - S0; h = t >> 4; w = t & 15; }
    float f;
    if (j < 16) f = (float)h * powf(10000.f, -(4.f * j) / 64.f);
    else        f = (float)w * powf(10000.f, -(4.f * (j - 16) + 2.f) / 64.f);
    cs[s * 32 + j] = cosf(f);
    sn[s * 32 + j] = sinf(f);
}

// ---------------- RoPE apply (in-place on q and k) ----------------
__global__ __launch_bounds__(256) void rope_apply_kernel(
    float* __restrict__ q, float* __restrict__ k,
    const float* __restrict__ cs, const float* __restrict__ sn)
{
    int idx = blockIdx.x * 256 + threadIdx.x;  // S*HEADS*32
    int s = idx / (HEADS * 32);
    int r = idx % (HEADS * 32);
    int hh = r >> 5; int j = r & 31;
    float c = cs[s * 32 + j], sv = sn[s * 32 + j];
    size_t base = (size_t)s * HID + hh * HD + j;
    float a = q[base], b = q[base + 32];
    q[base] = a * c - b * sv; q[base + 32] = b * c + a * sv;
    a = k[base]; b = k[base + 32];
    k[base] = a * c - b * sv; k[base + 32] = b * c + a * sv;
}

// ---------------- flash attention: block = (64 q-rows, head) ----------------
// Qs row-major [row][d] (pre-scaled), Ks transposed [d][row], Vs row-major.
// Scores: 4x4 per thread, rows tm..tm+3, cols tn..tn+3.
// Row reductions via shfl_xor within 16-lane groups; PV via shfl broadcast of P.
#define FPAD 68
__global__ __launch_bounds__(256) void flash_attn_kernel(
    const float* __restrict__ q, const float* __restrict__ k,
    const float* __restrict__ v, float* __restrict__ o)
{
    __shared__ float Qs[64][FPAD];
    __shared__ float Ks[64][FPAD];   // transposed: Ks[d][krow]
    __shared__ float Vs[64][64];
    int tile = blockIdx.x;
    int hh = blockIdx.y;
    int segStart, q0, nkt;
    if (tile < 16) { segStart = 0; q0 = tile << 6; nkt = 16; }
    else { segStart = S0; q0 = S0 + ((tile - 16) << 6); nkt = 8; }
    int t = threadIdx.x;
    int lane = t & 63;
    int tm = (t >> 4) << 2;   // row offset 0..60
    int tn = (t & 15) << 2;   // col offset 0..60

    // stage Q (row-major), fold in softmax scale
    #pragma unroll
    for (int ii = 0; ii < 4; ++ii) {
        int idx = t + (ii << 8);
        int r = idx >> 4, c4 = (idx & 15) << 2;
        float4 qv = *(const float4*)(q + (size_t)(q0 + r) * HID + hh * HD + c4);
        Qs[r][c4 + 0] = qv.x * SCALEV;
        Qs[r][c4 + 1] = qv.y * SCALEV;
        Qs[r][c4 + 2] = qv.z * SCALEV;
        Qs[r][c4 + 3] = qv.w * SCALEV;
    }

    float m_i[4], l_i[4], Oa[4][4];
    #pragma unroll
    for (int i = 0; i < 4; ++i) {
        m_i[i] = -1e30f; l_i[i] = 0.f;
        #pragma unroll
        for (int j = 0; j < 4; ++j) Oa[i][j] = 0.f;
    }

    for (int kt = 0; kt < nkt; ++kt) {
        int kbase = segStart + (kt << 6);
        #pragma unroll
        for (int ii = 0; ii < 4; ++ii) {
            int idx = t + (ii << 8);
            int r = idx >> 4, c4 = (idx & 15) << 2;
            float4 kv = *(const float4*)(k + (size_t)(kbase + r) * HID + hh * HD + c4);
            Ks[c4 + 0][r] = kv.x; Ks[c4 + 1][r] = kv.y;
            Ks[c4 + 2][r] = kv.z; Ks[c4 + 3][r] = kv.w;
            float4 vv = *(const float4*)(v + (size_t)(kbase + r) * HID + hh * HD + c4);
            *(float4*)&Vs[r][c4] = vv;
        }
        __syncthreads();

        // scores S[4][4]
        float Sc[4][4] = {{0.f,0.f,0.f,0.f},{0.f,0.f,0.f,0.f},{0.f,0.f,0.f,0.f},{0.f,0.f,0.f,0.f}};
        #pragma unroll
        for (int dq = 0; dq < 16; ++dq) {
            int d = dq << 2;
            float qa[4][4];
            #pragma unroll
            for (int i = 0; i < 4; ++i) {
                float4 qv = *(const float4*)&Qs[tm + i][d];
                qa[i][0] = qv.x; qa[i][1] = qv.y; qa[i][2] = qv.z; qa[i][3] = qv.w;
            }
            float kb[4][4];
            #pragma unroll
            for (int jj = 0; jj < 4; ++jj) {
                float4 kv = *(const float4*)&Ks[d + jj][tn];
                kb[jj][0] = kv.x; kb[jj][1] = kv.y; kb[jj][2] = kv.z; kb[jj][3] = kv.w;
            }
            #pragma unroll
            for (int i = 0; i < 4; ++i)
                #pragma unroll
                for (int j = 0; j < 4; ++j)
                    Sc[i][j] = fmaf(qa[i][0], kb[0][j],
                               fmaf(qa[i][1], kb[1][j],
                               fmaf(qa[i][2], kb[2][j],
                               fmaf(qa[i][3], kb[3][j], Sc[i][j]))));
        }

        // online softmax per row
        #pragma unroll
        for (int i = 0; i < 4; ++i) {
            float rm = fmaxf(fmaxf(Sc[i][0], Sc[i][1]), fmaxf(Sc[i][2], Sc[i][3]));
            #pragma unroll
            for (int msk = 1; msk < 16; msk <<= 1)
                rm = fmaxf(rm, __shfl_xor(rm, msk, 64));
            float mn = fmaxf(m_i[i], rm);
            float al = __expf(m_i[i] - mn);
            float rs = 0.f;
            #pragma unroll
            for (int j = 0; j < 4; ++j) {
                float p = __expf(Sc[i][j] - mn);
                Sc[i][j] = p; rs += p;
            }
            #pragma unroll
            for (int msk = 1; msk < 16; msk <<= 1)
                rs += __shfl_xor(rs, msk, 64);
            l_i[i] = l_i[i] * al + rs;
            m_i[i] = mn;
            #pragma unroll
            for (int j = 0; j < 4; ++j) Oa[i][j] *= al;
        }

        // PV: O[tm+i][tn+*] += P[tm+i][j] * V[j][tn+*], P via shfl
        #pragma unroll
        for (int jq = 0; jq < 16; ++jq) {
            int srcLane = (lane & 48) | jq;
            #pragma unroll
            for (int qq = 0; qq < 4; ++qq) {
                int j = (jq << 2) + qq;
                float4 vv = *(const float4*)&Vs[j][tn];
                #pragma unroll
                for (int i = 0; i < 4; ++i) {
                    float p = __shfl(Sc[i][qq], srcLane, 64);
                    Oa[i][0] = fmaf(p, vv.x, Oa[i][0]);
                    Oa[i][1] = fmaf(p, vv.y, Oa[i][1]);
                    Oa[i][2] = fmaf(p, vv.z, Oa[i][2]);
                    Oa[i][3] = fmaf(p, vv.w, Oa[i][3]);
                }
            }
        }
        __syncthreads();
    }

    // epilogue
    #pragma unroll
    for (int i = 0; i < 4; ++i) {
        float inv = 1.f / l_i[i];
        float4 ov = make_float4(Oa[i][0] * inv, Oa[i][1] * inv, Oa[i][2] * inv, Oa[i][3] * inv);
        *(float4*)(o + (size_t)(q0 + tm + i) * HID + hh * HD + tn) = ov;
    }
}

// ---------------- SiLU(g) * u -> g ----------------
__global__ __launch_bounds__(256) void silu_mul_kernel(
    float* __restrict__ g, const float* __restrict__ u, int n)
{
    int i = blockIdx.x * 256 + threadIdx.x;
    if (i < n) {
        float x = g[i];
        float sg = 1.f / (1.f + __expf(-x));
        g[i] = x * sg * u[i];
    }
}

// ---------------- copy to out ----------------
__global__ __launch_bounds__(256) void copy_kernel(
    const float* __restrict__ src, float* __restrict__ dst, int n)
{
    int i = blockIdx.x * 256 + threadIdx.x;
    if (i < n) dst[i] = src[i];
}

extern "C" void kernel_launch(void* const* d_in, const int* in_sizes, int n_in,
                              void* d_out, int out_size, void* d_ws, size_t ws_size,
                              hipStream_t stream)
{
    const float* img0        = (const float*)d_in[0];
    const float* img1        = (const float*)d_in[1];
    const float* conv_w      = (const float*)d_in[2];
    const float* ln_pre_w    = (const float*)d_in[3];
    const float* attn_norm_w = (const float*)d_in[4];
    const float* q_w         = (const float*)d_in[5];
    const float* k_w         = (const float*)d_in[6];
    const float* v_w         = (const float*)d_in[7];
    const float* o_w         = (const float*)d_in[8];
    const float* ffn_norm_w  = (const float*)d_in[9];
    const float* gate_w      = (const float*)d_in[10];
    const float* up_w        = (const float*)d_in[11];
    const float* down_w      = (const float*)d_in[12];

    float* ws = (float*)d_ws;
    const size_t SH = (size_t)S_TOT * HID;     // 1.57M
    const size_t SI = (size_t)S_TOT * INTER;   // 6.29M
    float* x  = ws;
    float* hn = x + SH;
    float* qb = hn + SH;
    float* kb = qb + SH;
    float* vb = kb + SH;
    float* ob = vb + SH;
    float* g  = ob + SH;
    float* u  = g + SI;
    float* cs = u + SI;
    float* sn = cs + (size_t)S_TOT * 32;
    float* P  = qb;  // im2col scratch reuses q buffer (used before q)

    dim3 blk(256);

    // patch embed
    im2col_kernel<<<S_TOT, blk, 0, stream>>>(img0, img1, P);
    {
        dim3 grid(S_TOT / BM, HID / BN);
        sgemm_btn<<<grid, blk, 0, stream>>>(P, conv_w, nullptr, x, S_TOT, HID, KCONV);
    }
    // ln_pre (in-place)
    rms_kernel<<<S_TOT, blk, 0, stream>>>(x, ln_pre_w, x, HID);
    // rope tables
    rope_tab_kernel<<<S_TOT, 32, 0, stream>>>(cs, sn);

    for (int l = 0; l < NLAYERS; ++l) {
        const float* qw = q_w + (size_t)l * HID * HID;
        const float* kw = k_w + (size_t)l * HID * HID;
        const float* vw = v_w + (size_t)l * HID * HID;
        const float* ow = o_w + (size_t)l * HID * HID;
        const float* gw = gate_w + (size_t)l * INTER * HID;
        const float* uw = up_w + (size_t)l * INTER * HID;
        const float* dw = down_w + (size_t)l * HID * INTER;

        rms_kernel<<<S_TOT, blk, 0, stream>>>(x, attn_norm_w + (size_t)l * HID, hn, HID);
        {
            dim3 grid(S_TOT / BM, HID / BN);
            sgemm_btn<<<grid, blk, 0, stream>>>(hn, qw, nullptr, qb, S_TOT, HID, HID);
            sgemm_btn<<<grid, blk, 0, stream>>>(hn, kw, nullptr, kb, S_TOT, HID, HID);
            sgemm_btn<<<grid, blk, 0, stream>>>(hn, vw, nullptr, vb, S_TOT, HID, HID);
        }
        rope_apply_kernel<<<(S_TOT * HEADS * 32) / 256, blk, 0, stream>>>(qb, kb, cs, sn);
        {
            dim3 agrid(24, HEADS);
            flash_attn_kernel<<<agrid, blk, 0, stream>>>(qb, kb, vb, ob);
        }
        {
            dim3 grid(S_TOT / BM, HID / BN);
            sgemm_btn<<<grid, blk, 0, stream>>>(ob, ow, x, x, S_TOT, HID, HID);  // residual
        }
        rms_kernel<<<S_TOT, blk, 0, stream>>>(x, ffn_norm_w + (size_t)l * HID, hn, HID);
        {
            dim3 grid(S_TOT / BM, INTER / BN);
            sgemm_btn<<<grid, blk, 0, stream>>>(hn, gw, nullptr, g, S_TOT, INTER, HID);
            sgemm_btn<<<grid, blk, 0, stream>>>(hn, uw, nullptr, u, S_TOT, INTER, HID);
        }
        silu_mul_kernel<<<(int)(SI / 256), blk, 0, stream>>>(g, u, (int)SI);
        {
            dim3 grid(S_TOT / BM, HID / BN);
            sgemm_btn<<<grid, blk, 0, stream>>>(g, dw, x, x, S_TOT, HID, INTER);  // residual
        }
    }
    copy_kernel<<<(int)(SH / 256), blk, 0, stream>>>(x, (float*)d_out, (int)SH);
}

// Round 3
// 1738.404 us; speedup vs baseline: 5.3849x; 2.7326x over previous
//
#include <hip/hip_runtime.h>
#include <hip/hip_bf16.h>
#include <math.h>

#define S_TOT 1536
#define S0    1024
#define HID   1024
#define HEADS 16
#define HD    64
#define INTER 4096
#define NLAYERS 4
#define KCONV 768
#define EPSV  1e-5f
#define SCALEV 0.125f
#define QKVS  3072   // fused qkv row stride

typedef __attribute__((ext_vector_type(8))) __bf16 bf16x8;
typedef __attribute__((ext_vector_type(4))) float f32x4;
typedef __attribute__((address_space(1))) void gvoid;
typedef __attribute__((address_space(3))) void lvoid;

__device__ __forceinline__ ushort f2bf(float f) {
    union { float f; unsigned u; } v; v.f = f;
    unsigned u = v.u;
    return (ushort)((u + 0x7FFFu + ((u >> 16) & 1u)) >> 16);
}
__device__ __forceinline__ float bf2f(ushort b) {
    union { unsigned u; float f; } v; v.u = ((unsigned)b) << 16;
    return v.f;
}

// ---------------- weight converts ----------------
__global__ __launch_bounds__(256) void cvt_kernel(
    const float* __restrict__ src, ushort* __restrict__ dst, int n4)
{
    int i = blockIdx.x * 256 + threadIdx.x;
    if (i < n4) {
        float4 v = ((const float4*)src)[i];
        ushort4 o;
        o.x = f2bf(v.x); o.y = f2bf(v.y); o.z = f2bf(v.z); o.w = f2bf(v.w);
        ((ushort4*)dst)[i] = o;
    }
}

// fused per-layer weight convert: dst = [qkv(3M) | o(1M) | gate(4M) | up(4M) | down(4M)]
__global__ __launch_bounds__(256) void cvt_layer_kernel(
    const float* __restrict__ qw, const float* __restrict__ kw,
    const float* __restrict__ vw, const float* __restrict__ ow,
    const float* __restrict__ gw, const float* __restrict__ uw,
    const float* __restrict__ dw, ushort* __restrict__ dst)
{
    int i = blockIdx.x * 256 + threadIdx.x;   // 4-elem group, 4M groups
    int e = i << 2;
    const float* src; int off;
    if      (e < (1  << 20)) { src = qw; off = e; }
    else if (e < (2  << 20)) { src = kw; off = e - (1 << 20); }
    else if (e < (3  << 20)) { src = vw; off = e - (2 << 20); }
    else if (e < (4  << 20)) { src = ow; off = e - (3 << 20); }
    else if (e < (8  << 20)) { src = gw; off = e - (4 << 20); }
    else if (e < (12 << 20)) { src = uw; off = e - (8 << 20); }
    else                     { src = dw; off = e - (12 << 20); }
    float4 v = *(const float4*)(src + off);
    ushort4 o;
    o.x = f2bf(v.x); o.y = f2bf(v.y); o.z = f2bf(v.z); o.w = f2bf(v.w);
    *(ushort4*)(dst + e) = o;
}

// ---------------- im2col (bf16 out) ----------------
__global__ __launch_bounds__(256) void im2col_kernel(
    const float* __restrict__ img0, const float* __restrict__ img1,
    ushort* __restrict__ P)
{
    int s = blockIdx.x;
    const float* img; int W, ph, pw;
    if (s < S0) { img = img0; W = 512; ph = s >> 5; pw = s & 31; }
    else { int t = s - S0; img = img1; W = 256; ph = t >> 4; pw = t & 15; }
    for (int k = threadIdx.x; k < KCONV; k += 256) {
        int c = k >> 8; int r = k & 255; int y = r >> 4; int x = r & 15;
        P[(size_t)s * KCONV + k] =
            f2bf(img[(size_t)c * 512 * W + (size_t)(ph * 16 + y) * W + (pw * 16 + x)]);
    }
}

// ---------------- MFMA bf16 GEMM: C[M][N] = A[M][K] * B[N][K]^T (+ D) ----------------
// 256 threads = 4 waves (2x2), wave tile (BM/2)x(BN/2), 16x16x32 mfma, BK=32.
template<int BM, int BN, bool OUT_BF16>
__global__ __launch_bounds__(256) void mfma_gemm_bt(
    const ushort* __restrict__ A, const ushort* __restrict__ B,
    const float* __restrict__ D, void* __restrict__ Cout,
    int M, int N, int K)
{
    constexpr int WMT = BM / 32;   // mfma tiles per wave (m)
    constexpr int WNT = BN / 32;
    __shared__ ushort As[BM * 32];
    __shared__ ushort Bs[BN * 32];
    const int t = threadIdx.x;
    const int bm = blockIdx.x * BM, bn = blockIdx.y * BN;
    const int wave = t >> 6, lane = t & 63;
    const int wm = (wave & 1) * (BM / 2), wn = (wave >> 1) * (BN / 2);
    const int frow = lane & 15, fq = lane >> 4;
    f32x4 acc[WMT][WNT];
    #pragma unroll
    for (int i = 0; i < WMT; ++i)
        #pragma unroll
        for (int j = 0; j < WNT; ++j) acc[i][j] = (f32x4){0.f, 0.f, 0.f, 0.f};

    for (int k0 = 0; k0 < K; k0 += 32) {
        __syncthreads();
        #pragma unroll
        for (int i = 0; i < BM * 4; i += 256) {
            int idx = t + i;
            int r = idx >> 2, c8 = (idx & 3) << 3;
            __builtin_amdgcn_global_load_lds(
                (gvoid*)(A + (size_t)(bm + r) * K + k0 + c8),
                (lvoid*)(As + idx * 8), 16, 0, 0);
        }
        #pragma unroll
        for (int i = 0; i < BN * 4; i += 256) {
            int idx = t + i;
            int r = idx >> 2, c8 = (idx & 3) << 3;
            __builtin_amdgcn_global_load_lds(
                (gvoid*)(B + (size_t)(bn + r) * K + k0 + c8),
                (lvoid*)(Bs + idx * 8), 16, 0, 0);
        }
        __syncthreads();
        bf16x8 af[WMT], bfr[WNT];
        #pragma unroll
        for (int i = 0; i < WMT; ++i)
            af[i] = *(const bf16x8*)(As + (wm + 16 * i + frow) * 32 + fq * 8);
        #pragma unroll
        for (int j = 0; j < WNT; ++j)
            bfr[j] = *(const bf16x8*)(Bs + (wn + 16 * j + frow) * 32 + fq * 8);
        #pragma unroll
        for (int i = 0; i < WMT; ++i)
            #pragma unroll
            for (int j = 0; j < WNT; ++j)
                acc[i][j] = __builtin_amdgcn_mfma_f32_16x16x32_bf16(
                    af[i], bfr[j], acc[i][j], 0, 0, 0);
    }
    #pragma unroll
    for (int i = 0; i < WMT; ++i) {
        #pragma unroll
        for (int j = 0; j < WNT; ++j) {
            #pragma unroll
            for (int r = 0; r < 4; ++r) {
                int row = bm + wm + 16 * i + fq * 4 + r;
                int col = bn + wn + 16 * j + frow;
                float vv = acc[i][j][r];
                if (D) vv += D[(size_t)row * N + col];
                if (OUT_BF16) ((ushort*)Cout)[(size_t)row * N + col] = f2bf(vv);
                else          ((float*)Cout)[(size_t)row * N + col] = vv;
            }
        }
    }
}

// ---------------- RMS norm fp32->fp32 (in place capable) ----------------
__global__ __launch_bounds__(256) void rms_kernel(
    const float* __restrict__ in, const float* __restrict__ w,
    float* __restrict__ out)
{
    int row = blockIdx.x;
    const float* xr = in + (size_t)row * HID;
    float ss = 0.f;
    for (int i = threadIdx.x; i < HID; i += 256) { float v = xr[i]; ss += v * v; }
    #pragma unroll
    for (int off = 32; off > 0; off >>= 1) ss += __shfl_down(ss, off, 64);
    __shared__ float red[4];
    int wid = threadIdx.x >> 6;
    if ((threadIdx.x & 63) == 0) red[wid] = ss;
    __syncthreads();
    if (threadIdx.x == 0)
        red[0] = rsqrtf((red[0] + red[1] + red[2] + red[3]) / HID + EPSV);
    __syncthreads();
    float rs = red[0];
    for (int i = threadIdx.x; i < HID; i += 256)
        out[(size_t)row * HID + i] = xr[i] * rs * w[i];
}

// ---------------- RMS norm fp32->bf16 ----------------
__global__ __launch_bounds__(256) void rms_bf_kernel(
    const float* __restrict__ in, const float* __restrict__ w,
    ushort* __restrict__ out)
{
    int row = blockIdx.x;
    const float* xr = in + (size_t)row * HID;
    float ss = 0.f;
    for (int i = threadIdx.x; i < HID; i += 256) { float v = xr[i]; ss += v * v; }
    #pragma unroll
    for (int off = 32; off > 0; off >>= 1) ss += __shfl_down(ss, off, 64);
    __shared__ float red[4];
    int wid = threadIdx.x >> 6;
    if ((threadIdx.x & 63) == 0) red[wid] = ss;
    __syncthreads();
    if (threadIdx.x == 0)
        red[0] = rsqrtf((red[0] + red[1] + red[2] + red[3]) / HID + EPSV);
    __syncthreads();
    float rs = red[0];
    for (int i = threadIdx.x; i < HID; i += 256)
        out[(size_t)row * HID + i] = f2bf(xr[i] * rs * w[i]);
}

// ---------------- RoPE tables ----------------
__global__ void rope_tab_kernel(float* __restrict__ cs, float* __restrict__ sn)
{
    int s = blockIdx.x; int j = threadIdx.x; // 32 threads
    int h, w;
    if (s < S0) { h = s >> 5; w = s & 31; }
    else { int t = s - S0; h = t >> 4; w = t & 15; }
    float f;
    if (j < 16) f = (float)h * powf(10000.f, -(4.f * j) / 64.f);
    else        f = (float)w * powf(10000.f, -(4.f * (j - 16) + 2.f) / 64.f);
    cs[s * 32 + j] = cosf(f);
    sn[s * 32 + j] = sinf(f);
}

// ---------------- RoPE apply on fused qkv (q and k parts) ----------------
__global__ __launch_bounds__(256) void rope_apply_kernel(
    float* __restrict__ qkv,
    const float* __restrict__ cs, const float* __restrict__ sn)
{
    int idx = blockIdx.x * 256 + threadIdx.x;  // S*HEADS*32
    int s = idx / (HEADS * 32);
    int r = idx % (HEADS * 32);
    int hh = r >> 5; int j = r & 31;
    float c = cs[s * 32 + j], sv = sn[s * 32 + j];
    size_t base = (size_t)s * QKVS + hh * HD + j;
    float a = qkv[base], b = qkv[base + 32];
    qkv[base] = a * c - b * sv; qkv[base + 32] = b * c + a * sv;
    a = qkv[base + 1024]; b = qkv[base + 1024 + 32];
    qkv[base + 1024] = a * c - b * sv; qkv[base + 1024 + 32] = b * c + a * sv;
}

// ---------------- flash attention on fused qkv, bf16 out ----------------
#define FPAD 68
__global__ __launch_bounds__(256) void flash_attn_kernel(
    const float* __restrict__ qkv, ushort* __restrict__ o)
{
    __shared__ float Qs[64][FPAD];
    __shared__ float Ks[64][FPAD];   // transposed: Ks[d][krow]
    __shared__ float Vs[64][64];
    int tile = blockIdx.x;
    int hh = blockIdx.y;
    int segStart, q0, nkt;
    if (tile < 16) { segStart = 0; q0 = tile << 6; nkt = 16; }
    else { segStart = S0; q0 = S0 + ((tile - 16) << 6); nkt = 8; }
    int t = threadIdx.x;
    int lane = t & 63;
    int tm = (t >> 4) << 2;
    int tn = (t & 15) << 2;

    const float* q = qkv;
    const float* k = qkv + 1024;
    const float* v = qkv + 2048;

    #pragma unroll
    for (int ii = 0; ii < 4; ++ii) {
        int idx = t + (ii << 8);
        int r = idx >> 4, c4 = (idx & 15) << 2;
        float4 qv = *(const float4*)(q + (size_t)(q0 + r) * QKVS + hh * HD + c4);
        Qs[r][c4 + 0] = qv.x * SCALEV;
        Qs[r][c4 + 1] = qv.y * SCALEV;
        Qs[r][c4 + 2] = qv.z * SCALEV;
        Qs[r][c4 + 3] = qv.w * SCALEV;
    }

    float m_i[4], l_i[4], Oa[4][4];
    #pragma unroll
    for (int i = 0; i < 4; ++i) {
        m_i[i] = -1e30f; l_i[i] = 0.f;
        #pragma unroll
        for (int j = 0; j < 4; ++j) Oa[i][j] = 0.f;
    }

    for (int kt = 0; kt < nkt; ++kt) {
        int kbase = segStart + (kt << 6);
        #pragma unroll
        for (int ii = 0; ii < 4; ++ii) {
            int idx = t + (ii << 8);
            int r = idx >> 4, c4 = (idx & 15) << 2;
            float4 kv = *(const float4*)(k + (size_t)(kbase + r) * QKVS + hh * HD + c4);
            Ks[c4 + 0][r] = kv.x; Ks[c4 + 1][r] = kv.y;
            Ks[c4 + 2][r] = kv.z; Ks[c4 + 3][r] = kv.w;
            float4 vv = *(const float4*)(v + (size_t)(kbase + r) * QKVS + hh * HD + c4);
            *(float4*)&Vs[r][c4] = vv;
        }
        __syncthreads();

        float Sc[4][4] = {{0.f,0.f,0.f,0.f},{0.f,0.f,0.f,0.f},{0.f,0.f,0.f,0.f},{0.f,0.f,0.f,0.f}};
        #pragma unroll
        for (int dq = 0; dq < 16; ++dq) {
            int d = dq << 2;
            float qa[4][4];
            #pragma unroll
            for (int i = 0; i < 4; ++i) {
                float4 qv = *(const float4*)&Qs[tm + i][d];
                qa[i][0] = qv.x; qa[i][1] = qv.y; qa[i][2] = qv.z; qa[i][3] = qv.w;
            }
            float kb[4][4];
            #pragma unroll
            for (int jj = 0; jj < 4; ++jj) {
                float4 kv = *(const float4*)&Ks[d + jj][tn];
                kb[jj][0] = kv.x; kb[jj][1] = kv.y; kb[jj][2] = kv.z; kb[jj][3] = kv.w;
            }
            #pragma unroll
            for (int i = 0; i < 4; ++i)
                #pragma unroll
                for (int j = 0; j < 4; ++j)
                    Sc[i][j] = fmaf(qa[i][0], kb[0][j],
                               fmaf(qa[i][1], kb[1][j],
                               fmaf(qa[i][2], kb[2][j],
                               fmaf(qa[i][3], kb[3][j], Sc[i][j]))));
        }

        #pragma unroll
        for (int i = 0; i < 4; ++i) {
            float rm = fmaxf(fmaxf(Sc[i][0], Sc[i][1]), fmaxf(Sc[i][2], Sc[i][3]));
            #pragma unroll
            for (int msk = 1; msk < 16; msk <<= 1)
                rm = fmaxf(rm, __shfl_xor(rm, msk, 64));
            float mn = fmaxf(m_i[i], rm);
            float al = __expf(m_i[i] - mn);
            float rs = 0.f;
            #pragma unroll
            for (int j = 0; j < 4; ++j) {
                float p = __expf(Sc[i][j] - mn);
                Sc[i][j] = p; rs += p;
            }
            #pragma unroll
            for (int msk = 1; msk < 16; msk <<= 1)
                rs += __shfl_xor(rs, msk, 64);
            l_i[i] = l_i[i] * al + rs;
            m_i[i] = mn;
            #pragma unroll
            for (int j = 0; j < 4; ++j) Oa[i][j] *= al;
        }

        #pragma unroll
        for (int jq = 0; jq < 16; ++jq) {
            int srcLane = (lane & 48) | jq;
            #pragma unroll
            for (int qq = 0; qq < 4; ++qq) {
                int j = (jq << 2) + qq;
                float4 vv = *(const float4*)&Vs[j][tn];
                #pragma unroll
                for (int i = 0; i < 4; ++i) {
                    float p = __shfl(Sc[i][qq], srcLane, 64);
                    Oa[i][0] = fmaf(p, vv.x, Oa[i][0]);
                    Oa[i][1] = fmaf(p, vv.y, Oa[i][1]);
                    Oa[i][2] = fmaf(p, vv.z, Oa[i][2]);
                    Oa[i][3] = fmaf(p, vv.w, Oa[i][3]);
                }
            }
        }
        __syncthreads();
    }

    #pragma unroll
    for (int i = 0; i < 4; ++i) {
        float inv = 1.f / l_i[i];
        ushort4 ov;
        ov.x = f2bf(Oa[i][0] * inv);
        ov.y = f2bf(Oa[i][1] * inv);
        ov.z = f2bf(Oa[i][2] * inv);
        ov.w = f2bf(Oa[i][3] * inv);
        *(ushort4*)(o + (size_t)(q0 + tm + i) * HID + hh * HD + tn) = ov;
    }
}

// ---------------- SiLU(gate)*up from fused bf16 [S][8192] -> bf16 [S][4096] ----------------
__global__ __launch_bounds__(256) void silu_mul_bf_kernel(
    const ushort* __restrict__ gu, ushort* __restrict__ gb)
{
    int i = blockIdx.x * 256 + threadIdx.x;   // S_TOT*INTER
    int s = i >> 12, c = i & 4095;
    float x = bf2f(gu[(size_t)s * 8192 + c]);
    float u = bf2f(gu[(size_t)s * 8192 + 4096 + c]);
    float sg = 1.f / (1.f + __expf(-x));
    gb[i] = f2bf(x * sg * u);
}

// ---------------- copy to out ----------------
__global__ __launch_bounds__(256) void copy_kernel(
    const float* __restrict__ src, float* __restrict__ dst, int n)
{
    int i = blockIdx.x * 256 + threadIdx.x;
    if (i < n) dst[i] = src[i];
}

extern "C" void kernel_launch(void* const* d_in, const int* in_sizes, int n_in,
                              void* d_out, int out_size, void* d_ws, size_t ws_size,
                              hipStream_t stream)
{
    const float* img0        = (const float*)d_in[0];
    const float* img1        = (const float*)d_in[1];
    const float* conv_w      = (const float*)d_in[2];
    const float* ln_pre_w    = (const float*)d_in[3];
    const float* attn_norm_w = (const float*)d_in[4];
    const float* q_w         = (const float*)d_in[5];
    const float* k_w         = (const float*)d_in[6];
    const float* v_w         = (const float*)d_in[7];
    const float* o_w         = (const float*)d_in[8];
    const float* ffn_norm_w  = (const float*)d_in[9];
    const float* gate_w      = (const float*)d_in[10];
    const float* up_w        = (const float*)d_in[11];
    const float* down_w      = (const float*)d_in[12];

    char* p = (char*)d_ws;
    float* x    = (float*)p;   p += (size_t)1572864 * 4;   // [1536][1024]
    float* qkv  = (float*)p;   p += (size_t)4718592 * 4;   // [1536][3072]
    float* cs   = (float*)p;   p += (size_t)49152 * 4;
    float* sn   = (float*)p;   p += (size_t)49152 * 4;
    ushort* hnb = (ushort*)p;  p += (size_t)1572864 * 2;   // [1536][1024]
    ushort* obb = (ushort*)p;  p += (size_t)1572864 * 2;   // [1536][1024]
    ushort* gub = (ushort*)p;  p += (size_t)12582912 * 2;  // [1536][8192]
    ushort* gb  = (ushort*)p;  p += (size_t)6291456 * 2;   // [1536][4096]
    ushort* Pb  = (ushort*)p;  p += (size_t)1179648 * 2;   // [1536][768]
    ushort* cvb = (ushort*)p;  p += (size_t)786432 * 2;    // conv_w bf16 [1024][768]
    ushort* wbuf= (ushort*)p;  p += (size_t)16777216 * 2;  // per-layer weights

    ushort* wqkv = wbuf;                 // [3072][1024]
    ushort* wo   = wbuf + 3145728;       // [1024][1024]
    ushort* wgu  = wbuf + 4194304;       // [8192][1024]
    ushort* wdn  = wbuf + 12582912;      // [1024][4096]

    dim3 blk(256);

    // conv weight convert + patch embed
    cvt_kernel<<<768, blk, 0, stream>>>(conv_w, cvb, 786432 / 4);
    im2col_kernel<<<S_TOT, blk, 0, stream>>>(img0, img1, Pb);
    mfma_gemm_bt<64, 64, false><<<dim3(24, 16), blk, 0, stream>>>(
        Pb, cvb, nullptr, x, S_TOT, HID, KCONV);
    rms_kernel<<<S_TOT, blk, 0, stream>>>(x, ln_pre_w, x);
    rope_tab_kernel<<<S_TOT, 32, 0, stream>>>(cs, sn);

    for (int l = 0; l < NLAYERS; ++l) {
        cvt_layer_kernel<<<16384, blk, 0, stream>>>(
            q_w + (size_t)l * 1048576, k_w + (size_t)l * 1048576,
            v_w + (size_t)l * 1048576, o_w + (size_t)l * 1048576,
            gate_w + (size_t)l * 4194304, up_w + (size_t)l * 4194304,
            down_w + (size_t)l * 4194304, wbuf);

        rms_bf_kernel<<<S_TOT, blk, 0, stream>>>(x, attn_norm_w + (size_t)l * HID, hnb);
        mfma_gemm_bt<128, 128, false><<<dim3(12, 24), blk, 0, stream>>>(
            hnb, wqkv, nullptr, qkv, S_TOT, QKVS, HID);
        rope_apply_kernel<<<(S_TOT * HEADS * 32) / 256, blk, 0, stream>>>(qkv, cs, sn);
        {
            dim3 agrid(24, HEADS);
            flash_attn_kernel<<<agrid, blk, 0, stream>>>(qkv, obb);
        }
        mfma_gemm_bt<64, 64, false><<<dim3(24, 16), blk, 0, stream>>>(
            obb, wo, x, x, S_TOT, HID, HID);   // +residual
        rms_bf_kernel<<<S_TOT, blk, 0, stream>>>(x, ffn_norm_w + (size_t)l * HID, hnb);
        mfma_gemm_bt<128, 128, true><<<dim3(12, 64), blk, 0, stream>>>(
            hnb, wgu, nullptr, gub, S_TOT, 2 * INTER, HID);
        silu_mul_bf_kernel<<<(S_TOT * INTER) / 256, blk, 0, stream>>>(gub, gb);
        mfma_gemm_bt<64, 64, false><<<dim3(24, 16), blk, 0, stream>>>(
            gb, wdn, x, x, S_TOT, HID, INTER);  // +residual
    }
    copy_kernel<<<(S_TOT * HID) / 256, blk, 0, stream>>>(x, (float*)d_out, S_TOT * HID);
}

// Round 4
// 1139.428 us; speedup vs baseline: 8.2157x; 1.5257x over previous
//
#include <hip/hip_runtime.h>
#include <hip/hip_bf16.h>
#include <math.h>

#define S_TOT 1536
#define S0    1024
#define HID   1024
#define HEADS 16
#define HD    64
#define INTER 4096
#define NLAYERS 4
#define KCONV 768
#define EPSV  1e-5f
#define SCALEV 0.125f
#define QKVS  3072   // fused qkv row stride (fp32 gemm out)
#define QKS   2048   // fused rope'd q|k bf16 row stride

typedef __attribute__((ext_vector_type(8))) __bf16 bf16x8;
typedef __attribute__((ext_vector_type(8))) unsigned short u16x8;
typedef __attribute__((ext_vector_type(4))) float f32x4;
typedef __attribute__((address_space(1))) void gvoid;
typedef __attribute__((address_space(3))) void lvoid;

__device__ __forceinline__ ushort f2bf(float f) {
    union { float f; unsigned u; } v; v.f = f;
    unsigned u = v.u;
    return (ushort)((u + 0x7FFFu + ((u >> 16) & 1u)) >> 16);
}
__device__ __forceinline__ float bf2f(ushort b) {
    union { unsigned u; float f; } v; v.u = ((unsigned)b) << 16;
    return v.f;
}

// ---------------- weight converts ----------------
__global__ __launch_bounds__(256) void cvt_kernel(
    const float* __restrict__ src, ushort* __restrict__ dst, int n4)
{
    int i = blockIdx.x * 256 + threadIdx.x;
    if (i < n4) {
        float4 v = ((const float4*)src)[i];
        ushort4 o;
        o.x = f2bf(v.x); o.y = f2bf(v.y); o.z = f2bf(v.z); o.w = f2bf(v.w);
        ((ushort4*)dst)[i] = o;
    }
}

// fused per-layer weight convert: dst = [qkv(3M) | o(1M) | gate(4M) | up(4M) | down(4M)]
__global__ __launch_bounds__(256) void cvt_layer_kernel(
    const float* __restrict__ qw, const float* __restrict__ kw,
    const float* __restrict__ vw, const float* __restrict__ ow,
    const float* __restrict__ gw, const float* __restrict__ uw,
    const float* __restrict__ dw, ushort* __restrict__ dst)
{
    int i = blockIdx.x * 256 + threadIdx.x;   // 4-elem group, 4M groups
    int e = i << 2;
    const float* src; int off;
    if      (e < (1  << 20)) { src = qw; off = e; }
    else if (e < (2  << 20)) { src = kw; off = e - (1 << 20); }
    else if (e < (3  << 20)) { src = vw; off = e - (2 << 20); }
    else if (e < (4  << 20)) { src = ow; off = e - (3 << 20); }
    else if (e < (8  << 20)) { src = gw; off = e - (4 << 20); }
    else if (e < (12 << 20)) { src = uw; off = e - (8 << 20); }
    else                     { src = dw; off = e - (12 << 20); }
    float4 v = *(const float4*)(src + off);
    ushort4 o;
    o.x = f2bf(v.x); o.y = f2bf(v.y); o.z = f2bf(v.z); o.w = f2bf(v.w);
    *(ushort4*)(dst + e) = o;
}

// ---------------- im2col (bf16 out) ----------------
__global__ __launch_bounds__(256) void im2col_kernel(
    const float* __restrict__ img0, const float* __restrict__ img1,
    ushort* __restrict__ P)
{
    int s = blockIdx.x;
    const float* img; int W, ph, pw;
    if (s < S0) { img = img0; W = 512; ph = s >> 5; pw = s & 31; }
    else { int t = s - S0; img = img1; W = 256; ph = t >> 4; pw = t & 15; }
    for (int k = threadIdx.x; k < KCONV; k += 256) {
        int c = k >> 8; int r = k & 255; int y = r >> 4; int x = r & 15;
        P[(size_t)s * KCONV + k] =
            f2bf(img[(size_t)c * 512 * W + (size_t)(ph * 16 + y) * W + (pw * 16 + x)]);
    }
}

// ---------------- MFMA bf16 GEMM: C[M][N] = A[M][K] * B[N][K]^T (+ D) ----------------
template<int BM, int BN, bool OUT_BF16>
__global__ __launch_bounds__(256) void mfma_gemm_bt(
    const ushort* __restrict__ A, const ushort* __restrict__ B,
    const float* __restrict__ D, void* __restrict__ Cout,
    int M, int N, int K)
{
    constexpr int WMT = BM / 32;
    constexpr int WNT = BN / 32;
    __shared__ ushort As[BM * 32];
    __shared__ ushort Bs[BN * 32];
    const int t = threadIdx.x;
    const int bm = blockIdx.x * BM, bn = blockIdx.y * BN;
    const int wave = t >> 6, lane = t & 63;
    const int wm = (wave & 1) * (BM / 2), wn = (wave >> 1) * (BN / 2);
    const int frow = lane & 15, fq = lane >> 4;
    f32x4 acc[WMT][WNT];
    #pragma unroll
    for (int i = 0; i < WMT; ++i)
        #pragma unroll
        for (int j = 0; j < WNT; ++j) acc[i][j] = (f32x4){0.f, 0.f, 0.f, 0.f};

    for (int k0 = 0; k0 < K; k0 += 32) {
        __syncthreads();
        #pragma unroll
        for (int i = 0; i < BM * 4; i += 256) {
            int idx = t + i;
            int r = idx >> 2, c8 = (idx & 3) << 3;
            __builtin_amdgcn_global_load_lds(
                (gvoid*)(A + (size_t)(bm + r) * K + k0 + c8),
                (lvoid*)(As + idx * 8), 16, 0, 0);
        }
        #pragma unroll
        for (int i = 0; i < BN * 4; i += 256) {
            int idx = t + i;
            int r = idx >> 2, c8 = (idx & 3) << 3;
            __builtin_amdgcn_global_load_lds(
                (gvoid*)(B + (size_t)(bn + r) * K + k0 + c8),
                (lvoid*)(Bs + idx * 8), 16, 0, 0);
        }
        __syncthreads();
        bf16x8 af[WMT], bfr[WNT];
        #pragma unroll
        for (int i = 0; i < WMT; ++i)
            af[i] = *(const bf16x8*)(As + (wm + 16 * i + frow) * 32 + fq * 8);
        #pragma unroll
        for (int j = 0; j < WNT; ++j)
            bfr[j] = *(const bf16x8*)(Bs + (wn + 16 * j + frow) * 32 + fq * 8);
        #pragma unroll
        for (int i = 0; i < WMT; ++i)
            #pragma unroll
            for (int j = 0; j < WNT; ++j)
                acc[i][j] = __builtin_amdgcn_mfma_f32_16x16x32_bf16(
                    af[i], bfr[j], acc[i][j], 0, 0, 0);
    }
    #pragma unroll
    for (int i = 0; i < WMT; ++i) {
        #pragma unroll
        for (int j = 0; j < WNT; ++j) {
            #pragma unroll
            for (int r = 0; r < 4; ++r) {
                int row = bm + wm + 16 * i + fq * 4 + r;
                int col = bn + wn + 16 * j + frow;
                float vv = acc[i][j][r];
                if (D) vv += D[(size_t)row * N + col];
                if (OUT_BF16) ((ushort*)Cout)[(size_t)row * N + col] = f2bf(vv);
                else          ((float*)Cout)[(size_t)row * N + col] = vv;
            }
        }
    }
}

// ---------------- RMS norm fp32->fp32 ----------------
__global__ __launch_bounds__(256) void rms_kernel(
    const float* __restrict__ in, const float* __restrict__ w,
    float* __restrict__ out)
{
    int row = blockIdx.x;
    const float* xr = in + (size_t)row * HID;
    float ss = 0.f;
    for (int i = threadIdx.x; i < HID; i += 256) { float v = xr[i]; ss += v * v; }
    #pragma unroll
    for (int off = 32; off > 0; off >>= 1) ss += __shfl_down(ss, off, 64);
    __shared__ float red[4];
    int wid = threadIdx.x >> 6;
    if ((threadIdx.x & 63) == 0) red[wid] = ss;
    __syncthreads();
    if (threadIdx.x == 0)
        red[0] = rsqrtf((red[0] + red[1] + red[2] + red[3]) / HID + EPSV);
    __syncthreads();
    float rs = red[0];
    for (int i = threadIdx.x; i < HID; i += 256)
        out[(size_t)row * HID + i] = xr[i] * rs * w[i];
}

// ---------------- RMS norm fp32->bf16 ----------------
__global__ __launch_bounds__(256) void rms_bf_kernel(
    const float* __restrict__ in, const float* __restrict__ w,
    ushort* __restrict__ out)
{
    int row = blockIdx.x;
    const float* xr = in + (size_t)row * HID;
    float ss = 0.f;
    for (int i = threadIdx.x; i < HID; i += 256) { float v = xr[i]; ss += v * v; }
    #pragma unroll
    for (int off = 32; off > 0; off >>= 1) ss += __shfl_down(ss, off, 64);
    __shared__ float red[4];
    int wid = threadIdx.x >> 6;
    if ((threadIdx.x & 63) == 0) red[wid] = ss;
    __syncthreads();
    if (threadIdx.x == 0)
        red[0] = rsqrtf((red[0] + red[1] + red[2] + red[3]) / HID + EPSV);
    __syncthreads();
    float rs = red[0];
    for (int i = threadIdx.x; i < HID; i += 256)
        out[(size_t)row * HID + i] = f2bf(xr[i] * rs * w[i]);
}

// ---------------- RoPE tables ----------------
__global__ void rope_tab_kernel(float* __restrict__ cs, float* __restrict__ sn)
{
    int s = blockIdx.x; int j = threadIdx.x; // 32 threads
    int h, w;
    if (s < S0) { h = s >> 5; w = s & 31; }
    else { int t = s - S0; h = t >> 4; w = t & 15; }
    float f;
    if (j < 16) f = (float)h * powf(10000.f, -(4.f * j) / 64.f);
    else        f = (float)w * powf(10000.f, -(4.f * (j - 16) + 2.f) / 64.f);
    cs[s * 32 + j] = cosf(f);
    sn[s * 32 + j] = sinf(f);
}

// ---------------- RoPE q,k fp32 -> bf16 qkb[1536][2048] ----------------
__global__ __launch_bounds__(256) void rope_bf_kernel(
    const float* __restrict__ qkv, ushort* __restrict__ qkb,
    const float* __restrict__ cs, const float* __restrict__ sn)
{
    int idx = blockIdx.x * 256 + threadIdx.x;   // S_TOT*2048
    int s = idx >> 11, c = idx & 2047;
    int part = c >> 10, cc = c & 1023;
    int hh = cc >> 6, d = cc & 63, j = d & 31;
    size_t base = (size_t)s * QKVS + part * 1024 + hh * HD;
    float xa = qkv[base + j], xb = qkv[base + 32 + j];
    float cv = cs[s * 32 + j], sv = sn[s * 32 + j];
    float out = (d < 32) ? (xa * cv - xb * sv) : (xb * cv + xa * sv);
    qkb[idx] = f2bf(out);
}

// ---------------- V transpose fp32 qkv -> bf16 vT[head][d][s] ----------------
__global__ __launch_bounds__(256) void vtrans_kernel(
    const float* __restrict__ qkv, ushort* __restrict__ vT)
{
    __shared__ float T[64][65];
    int st = blockIdx.x;   // s-tile (24)
    int hh = blockIdx.y;   // head
    int s0 = st << 6;
    int t = threadIdx.x;
    #pragma unroll
    for (int i = 0; i < 16; i += 4) {
        int u = t + ((i >> 2) << 8);     // 4 iters of 256 -> 1024 float4 units
        int r = u >> 4, c4 = (u & 15) << 2;
        float4 v = *(const float4*)(qkv + (size_t)(s0 + r) * QKVS + 2048 + hh * HD + c4);
        T[r][c4 + 0] = v.x; T[r][c4 + 1] = v.y; T[r][c4 + 2] = v.z; T[r][c4 + 3] = v.w;
    }
    __syncthreads();
    int d = t >> 2, sg = (t & 3) << 4;
    ushort buf[16];
    #pragma unroll
    for (int j = 0; j < 16; ++j) buf[j] = f2bf(T[sg + j][d]);
    ushort* dst = vT + ((size_t)hh * HD + d) * S_TOT + s0 + sg;
    *(u16x8*)dst = *(u16x8*)buf;
    *(u16x8*)(dst + 8) = *(u16x8*)(buf + 8);
}

// ---------------- MFMA flash attention ----------------
// block = (q-tile of 64, head); 4 waves x 16 q-rows; k-tiles of 64 keys.
// Ks[key][d] pitch 72, Vt[d][key] pitch 72, Ps[wave][q][key] pitch 72 (all bf16).
__global__ __launch_bounds__(256) void flash_mfma_kernel(
    const ushort* __restrict__ qkb, const ushort* __restrict__ vT,
    ushort* __restrict__ o)
{
    __shared__ ushort Ks[64 * 72];
    __shared__ ushort Vt[64 * 72];
    __shared__ ushort Ps[4 * 16 * 72];
    int tile = blockIdx.x;
    int hh = blockIdx.y;
    int segStart, q0, nkt;
    if (tile < 16) { segStart = 0; q0 = tile << 6; nkt = 16; }
    else { segStart = S0; q0 = S0 + ((tile - 16) << 6); nkt = 8; }
    const int t = threadIdx.x;
    const int wave = t >> 6, lane = t & 63;
    const int c = lane & 15, fq = lane >> 4;
    const int wq = wave << 4;
    ushort* Pw = Ps + wave * 16 * 72;

    // Q fragments direct from global (A-operand layout), reused across all k-tiles
    bf16x8 qf[2];
    #pragma unroll
    for (int ks = 0; ks < 2; ++ks)
        qf[ks] = *(const bf16x8*)(qkb + (size_t)(q0 + wq + c) * QKS + hh * HD + ks * 32 + fq * 8);

    float m_i[4], l_i[4];
    f32x4 accO[4];
    #pragma unroll
    for (int r = 0; r < 4; ++r) { m_i[r] = -1e30f; l_i[r] = 0.f; }
    #pragma unroll
    for (int nt = 0; nt < 4; ++nt) accO[nt] = (f32x4){0.f, 0.f, 0.f, 0.f};

    for (int kt = 0; kt < nkt; ++kt) {
        int kbase = segStart + (kt << 6);
        __syncthreads();
        // stage K rows (bf16, row-major) and Vt rows (bf16, d-major from global vT)
        #pragma unroll
        for (int i = 0; i < 2; ++i) {
            int u = t + (i << 8);            // 512 ushort8 units
            int r = u >> 3, c8 = (u & 7) << 3;
            u16x8 kv = *(const u16x8*)(qkb + (size_t)(kbase + r) * QKS + 1024 + hh * HD + c8);
            *(u16x8*)(Ks + r * 72 + c8) = kv;
            u16x8 vv = *(const u16x8*)(vT + ((size_t)hh * HD + r) * S_TOT + kbase + c8);
            *(u16x8*)(Vt + r * 72 + c8) = vv;
        }
        __syncthreads();

        // QK^T: scores C[q=fq*4+r][key=nt*16+c]
        f32x4 acc[4];
        #pragma unroll
        for (int nt = 0; nt < 4; ++nt) acc[nt] = (f32x4){0.f, 0.f, 0.f, 0.f};
        #pragma unroll
        for (int ks = 0; ks < 2; ++ks) {
            #pragma unroll
            for (int nt = 0; nt < 4; ++nt) {
                bf16x8 bfr = *(const bf16x8*)(Ks + (nt * 16 + c) * 72 + ks * 32 + fq * 8);
                acc[nt] = __builtin_amdgcn_mfma_f32_16x16x32_bf16(qf[ks], bfr, acc[nt], 0, 0, 0);
            }
        }

        // online softmax (per q-row r), P -> LDS (bf16, A-operand layout)
        #pragma unroll
        for (int r = 0; r < 4; ++r) {
            float s0v = acc[0][r] * SCALEV, s1v = acc[1][r] * SCALEV;
            float s2v = acc[2][r] * SCALEV, s3v = acc[3][r] * SCALEV;
            float rm = fmaxf(fmaxf(s0v, s1v), fmaxf(s2v, s3v));
            #pragma unroll
            for (int msk = 1; msk < 16; msk <<= 1)
                rm = fmaxf(rm, __shfl_xor(rm, msk, 64));
            float mn = fmaxf(m_i[r], rm);
            float al = __expf(m_i[r] - mn);
            float p0 = __expf(s0v - mn), p1 = __expf(s1v - mn);
            float p2 = __expf(s2v - mn), p3 = __expf(s3v - mn);
            float rs = p0 + p1 + p2 + p3;
            #pragma unroll
            for (int msk = 1; msk < 16; msk <<= 1)
                rs += __shfl_xor(rs, msk, 64);
            l_i[r] = l_i[r] * al + rs;
            m_i[r] = mn;
            #pragma unroll
            for (int nt = 0; nt < 4; ++nt) accO[nt][r] *= al;
            int qrow = (fq << 2) + r;
            Pw[qrow * 72 + 0  + c] = f2bf(p0);
            Pw[qrow * 72 + 16 + c] = f2bf(p1);
            Pw[qrow * 72 + 32 + c] = f2bf(p2);
            Pw[qrow * 72 + 48 + c] = f2bf(p3);
        }

        // PV: O[q][d=nt*16+c] += P[q][key] * V[key][d]
        #pragma unroll
        for (int ks = 0; ks < 2; ++ks) {
            bf16x8 pa = *(const bf16x8*)(Pw + c * 72 + ks * 32 + fq * 8);
            #pragma unroll
            for (int nt = 0; nt < 4; ++nt) {
                bf16x8 bv = *(const bf16x8*)(Vt + (nt * 16 + c) * 72 + ks * 32 + fq * 8);
                accO[nt] = __builtin_amdgcn_mfma_f32_16x16x32_bf16(pa, bv, accO[nt], 0, 0, 0);
            }
        }
    }

    // epilogue
    #pragma unroll
    for (int r = 0; r < 4; ++r) {
        float inv = 1.f / l_i[r];
        int row = q0 + wq + (fq << 2) + r;
        #pragma unroll
        for (int nt = 0; nt < 4; ++nt)
            o[(size_t)row * HID + hh * HD + nt * 16 + c] = f2bf(accO[nt][r] * inv);
    }
}

// ---------------- SiLU(gate)*up from fused bf16 [S][8192] -> bf16 [S][4096] ----------------
__global__ __launch_bounds__(256) void silu_mul_bf_kernel(
    const ushort* __restrict__ gu, ushort* __restrict__ gb)
{
    int i = blockIdx.x * 256 + threadIdx.x;   // S_TOT*INTER
    int s = i >> 12, cc = i & 4095;
    float x = bf2f(gu[(size_t)s * 8192 + cc]);
    float u = bf2f(gu[(size_t)s * 8192 + 4096 + cc]);
    float sg = 1.f / (1.f + __expf(-x));
    gb[i] = f2bf(x * sg * u);
}

// ---------------- copy to out ----------------
__global__ __launch_bounds__(256) void copy_kernel(
    const float* __restrict__ src, float* __restrict__ dst, int n)
{
    int i = blockIdx.x * 256 + threadIdx.x;
    if (i < n) dst[i] = src[i];
}

extern "C" void kernel_launch(void* const* d_in, const int* in_sizes, int n_in,
                              void* d_out, int out_size, void* d_ws, size_t ws_size,
                              hipStream_t stream)
{
    const float* img0        = (const float*)d_in[0];
    const float* img1        = (const float*)d_in[1];
    const float* conv_w      = (const float*)d_in[2];
    const float* ln_pre_w    = (const float*)d_in[3];
    const float* attn_norm_w = (const float*)d_in[4];
    const float* q_w         = (const float*)d_in[5];
    const float* k_w         = (const float*)d_in[6];
    const float* v_w         = (const float*)d_in[7];
    const float* o_w         = (const float*)d_in[8];
    const float* ffn_norm_w  = (const float*)d_in[9];
    const float* gate_w      = (const float*)d_in[10];
    const float* up_w        = (const float*)d_in[11];
    const float* down_w      = (const float*)d_in[12];

    char* p = (char*)d_ws;
    float* x    = (float*)p;   p += (size_t)1572864 * 4;   // [1536][1024]
    float* qkv  = (float*)p;   p += (size_t)4718592 * 4;   // [1536][3072]
    float* cs   = (float*)p;   p += (size_t)49152 * 4;
    float* sn   = (float*)p;   p += (size_t)49152 * 4;
    ushort* qkb = (ushort*)p;  p += (size_t)3145728 * 2;   // [1536][2048] rope'd q|k bf16
    ushort* vTb = (ushort*)p;  p += (size_t)1572864 * 2;   // [16][64][1536] V^T bf16
    ushort* hnb = (ushort*)p;  p += (size_t)1572864 * 2;   // [1536][1024]
    ushort* obb = (ushort*)p;  p += (size_t)1572864 * 2;   // [1536][1024]
    ushort* gub = (ushort*)p;  p += (size_t)12582912 * 2;  // [1536][8192]
    ushort* gb  = (ushort*)p;  p += (size_t)6291456 * 2;   // [1536][4096]
    ushort* Pb  = (ushort*)p;  p += (size_t)1179648 * 2;   // [1536][768]
    ushort* cvb = (ushort*)p;  p += (size_t)786432 * 2;    // conv_w bf16
    ushort* wbuf= (ushort*)p;  p += (size_t)16777216 * 2;  // per-layer weights

    ushort* wqkv = wbuf;                 // [3072][1024]
    ushort* wo   = wbuf + 3145728;       // [1024][1024]
    ushort* wgu  = wbuf + 4194304;       // [8192][1024]
    ushort* wdn  = wbuf + 12582912;      // [1024][4096]

    dim3 blk(256);

    cvt_kernel<<<768, blk, 0, stream>>>(conv_w, cvb, 786432 / 4);
    im2col_kernel<<<S_TOT, blk, 0, stream>>>(img0, img1, Pb);
    mfma_gemm_bt<64, 64, false><<<dim3(24, 16), blk, 0, stream>>>(
        Pb, cvb, nullptr, x, S_TOT, HID, KCONV);
    rms_kernel<<<S_TOT, blk, 0, stream>>>(x, ln_pre_w, x);
    rope_tab_kernel<<<S_TOT, 32, 0, stream>>>(cs, sn);

    for (int l = 0; l < NLAYERS; ++l) {
        cvt_layer_kernel<<<16384, blk, 0, stream>>>(
            q_w + (size_t)l * 1048576, k_w + (size_t)l * 1048576,
            v_w + (size_t)l * 1048576, o_w + (size_t)l * 1048576,
            gate_w + (size_t)l * 4194304, up_w + (size_t)l * 4194304,
            down_w + (size_t)l * 4194304, wbuf);

        rms_bf_kernel<<<S_TOT, blk, 0, stream>>>(x, attn_norm_w + (size_t)l * HID, hnb);
        mfma_gemm_bt<128, 128, false><<<dim3(12, 24), blk, 0, stream>>>(
            hnb, wqkv, nullptr, qkv, S_TOT, QKVS, HID);
        rope_bf_kernel<<<(S_TOT * QKS) / 256, blk, 0, stream>>>(qkv, qkb, cs, sn);
        vtrans_kernel<<<dim3(24, HEADS), blk, 0, stream>>>(qkv, vTb);
        flash_mfma_kernel<<<dim3(24, HEADS), blk, 0, stream>>>(qkb, vTb, obb);
        mfma_gemm_bt<64, 64, false><<<dim3(24, 16), blk, 0, stream>>>(
            obb, wo, x, x, S_TOT, HID, HID);   // +residual
        rms_bf_kernel<<<S_TOT, blk, 0, stream>>>(x, ffn_norm_w + (size_t)l * HID, hnb);
        mfma_gemm_bt<128, 128, true><<<dim3(12, 64), blk, 0, stream>>>(
            hnb, wgu, nullptr, gub, S_TOT, 2 * INTER, HID);
        silu_mul_bf_kernel<<<(S_TOT * INTER) / 256, blk, 0, stream>>>(gub, gb);
        mfma_gemm_bt<64, 64, false><<<dim3(24, 16), blk, 0, stream>>>(
            gb, wdn, x, x, S_TOT, HID, INTER);  // +residual
    }
    copy_kernel<<<(S_TOT * HID) / 256, blk, 0, stream>>>(x, (float*)d_out, S_TOT * HID);
}